// Round 1
// baseline (1320.499 us; speedup 1.0000x reference)
//
#include <hip/hip_runtime.h>
#include <math.h>

#define NEG_SLOPE 0.05f

__device__ __forceinline__ float leaky(float x){ return x >= 0.f ? x : NEG_SLOPE * x; }

// monotone float -> uint map so atomicMax(unsigned) orders like float
__device__ __forceinline__ unsigned encodeF(float f){
    unsigned b = __float_as_uint(f);
    return (b & 0x80000000u) ? ~b : (b | 0x80000000u);
}
__device__ __forceinline__ float decodeF(unsigned u){
    return (u & 0x80000000u) ? __uint_as_float(u & 0x7fffffffu) : __uint_as_float(~u);
}
#define ENC_NEG_INF 0x007fffffu  // encodeF(-inf)

// ---------------- K0: zero/init workspace (ws is poisoned 0xAA each call) ----------------
__global__ __launch_bounds__(256) void k_init(float* s_n, float* s_e, float* cnt_n, float* cnt_e,
                                              unsigned* m_e, float* acc_n, float* acc_e, int N){
    int t = blockIdx.x * blockDim.x + threadIdx.x;
    int stride = gridDim.x * blockDim.x;
    int total = N * 64;
    for (int i = t; i < total; i += stride){ acc_n[i] = 0.f; acc_e[i] = 0.f; }
    for (int i = t; i < N; i += stride){
        s_n[i] = 0.f; s_e[i] = 0.f; cnt_n[i] = 0.f; cnt_e[i] = 0.f; m_e[i] = ENC_NEG_INF;
    }
}

// ---------------- K1: h = x @ Wn^T, hi/hj/he scalars, m_n init with self-loop ----------------
__global__ __launch_bounds__(256) void k_node(const float* __restrict__ x, const float* __restrict__ Wn,
        const float* __restrict__ a_node, const float* __restrict__ a_edge,
        float* __restrict__ h, float* __restrict__ hi, float* __restrict__ hj, float* __restrict__ he,
        unsigned* __restrict__ m_n, int N){
    __shared__ float Wt[128 * 64];          // transposed: Wt[f*64+d] = Wn[d*128+f]
    for (int i = threadIdx.x; i < 128 * 64; i += 256){
        int f = i >> 6, d = i & 63;
        Wt[i] = Wn[d * 128 + f];
    }
    __syncthreads();
    int lane = threadIdx.x & 63;
    int node = (blockIdx.x * 256 + threadIdx.x) >> 6;   // one wave per node
    if (node >= N) return;
    float xv0 = x[(size_t)node * 128 + lane];
    float xv1 = x[(size_t)node * 128 + 64 + lane];
    float acc = 0.f;
    #pragma unroll
    for (int f = 0; f < 64; f++){
        float xf = __shfl(xv0, f);
        acc = fmaf(xf, Wt[f * 64 + lane], acc);
    }
    #pragma unroll
    for (int f = 0; f < 64; f++){
        float xf = __shfl(xv1, f);
        acc = fmaf(xf, Wt[(64 + f) * 64 + lane], acc);
    }
    h[(size_t)node * 64 + lane] = acc;
    float p1 = acc * a_node[lane];
    float p2 = acc * a_node[64 + lane];
    float p3 = acc * a_edge[lane];
    #pragma unroll
    for (int k = 1; k < 64; k <<= 1){
        p1 += __shfl_xor(p1, k);
        p2 += __shfl_xor(p2, k);
        p3 += __shfl_xor(p3, k);
    }
    if (lane == 0){
        hi[node] = p1; hj[node] = p2; he[node] = p3;
        m_n[node] = encodeF(leaky(p1 + p2));   // self-loop seeds the node-branch max
    }
}

// ---------------- K2: ge[k] = ea[k] . (We^T a_edge[64:]); segment maxes; counts ----------------
__global__ __launch_bounds__(256) void k_max(const float* __restrict__ ea, const int* __restrict__ idx,
        const float* __restrict__ We, const float* __restrict__ a_edge,
        const float* __restrict__ hi, const float* __restrict__ hj, const float* __restrict__ he,
        float* __restrict__ ge, unsigned* __restrict__ m_n, unsigned* __restrict__ m_e,
        float* __restrict__ cnt_n, float* __restrict__ cnt_e, int E){
    __shared__ float v[64];
    if (threadIdx.x < 64){
        float s = 0.f;
        for (int d = 0; d < 64; d++) s = fmaf(We[d * 64 + threadIdx.x], a_edge[64 + d], s);
        v[threadIdx.x] = s;
    }
    __syncthreads();
    int k = blockIdx.x * 256 + threadIdx.x;
    if (k >= E) return;
    const float4* row = (const float4*)(ea + (size_t)k * 64);
    float s = 0.f;
    #pragma unroll
    for (int q = 0; q < 16; q++){
        float4 r = row[q];
        s = fmaf(r.x, v[4*q+0], s);
        s = fmaf(r.y, v[4*q+1], s);
        s = fmaf(r.z, v[4*q+2], s);
        s = fmaf(r.w, v[4*q+3], s);
    }
    ge[k] = s;
    int i0 = idx[k], i1 = idx[E + k];
    float en = leaky(hi[i0] + hj[i1]);
    atomicMax(&m_n[i0], encodeF(en));
    float e0 = leaky(he[i0] + s);
    float e1 = leaky(he[i1] + s);
    atomicMax(&m_e[i0], encodeF(e0));
    atomicMax(&m_e[i1], encodeF(e1));
    atomicAdd(&cnt_n[i0], 1.f);
    atomicAdd(&cnt_e[i0], 1.f);
    atomicAdd(&cnt_e[i1], 1.f);
}

// ---------------- K3: accumulate softmax numerators + denominators (atomic scatter) ----------------
__global__ __launch_bounds__(256) void k_acc(const float* __restrict__ ea, const int* __restrict__ idx,
        const float* __restrict__ We,
        const float* __restrict__ h, const float* __restrict__ hi, const float* __restrict__ hj,
        const float* __restrict__ he, const float* __restrict__ ge,
        const unsigned* __restrict__ m_n, const unsigned* __restrict__ m_e,
        float* __restrict__ s_n, float* __restrict__ s_e,
        float* __restrict__ acc_n, float* __restrict__ acc_e, int E){
    __shared__ float Wet[64 * 64];   // Wet[f*64+d] = We[d*64+f]
    for (int i = threadIdx.x; i < 64 * 64; i += 256){
        int f = i >> 6, d = i & 63;
        Wet[i] = We[d * 64 + f];
    }
    __syncthreads();
    int lane = threadIdx.x & 63;
    int wid = (blockIdx.x * 256 + threadIdx.x) >> 6;
    int nwaves = gridDim.x * 4;
    for (int k = wid; k < E; k += nwaves){
        int i0 = idx[k], i1 = idx[E + k];
        float eav = ea[(size_t)k * 64 + lane];
        // node->node branch
        float w_n = __expf(leaky(hi[i0] + hj[i1]) - decodeF(m_n[i0]));
        float hval = h[(size_t)i1 * 64 + lane];
        atomicAdd(&acc_n[(size_t)i0 * 64 + lane], w_n * hval);
        // edge->node branch: recompute g row in-register (shuffle-broadcast GEMV)
        float gd = 0.f;
        #pragma unroll
        for (int f = 0; f < 64; f++){
            float eaf = __shfl(eav, f);
            gd = fmaf(eaf, Wet[f * 64 + lane], gd);
        }
        float gev = ge[k];
        float w0 = __expf(leaky(he[i0] + gev) - decodeF(m_e[i0]));
        float w1 = __expf(leaky(he[i1] + gev) - decodeF(m_e[i1]));
        atomicAdd(&acc_e[(size_t)i0 * 64 + lane], w0 * gd);
        atomicAdd(&acc_e[(size_t)i1 * 64 + lane], w1 * gd);
        if (lane == 0){
            atomicAdd(&s_n[i0], w_n);
            atomicAdd(&s_e[i0], w0);
            atomicAdd(&s_e[i1], w1);
        }
    }
}

// ---------------- K4: finalize (fold self-loop, divide, leaky, write) ----------------
__global__ __launch_bounds__(256) void k_final(const float* __restrict__ h,
        const float* __restrict__ hi, const float* __restrict__ hj,
        const unsigned* __restrict__ m_n,
        const float* __restrict__ s_n, const float* __restrict__ s_e,
        const float* __restrict__ cnt_n, const float* __restrict__ cnt_e,
        const float* __restrict__ acc_n, const float* __restrict__ acc_e,
        float* __restrict__ out, int N){
    int lane = threadIdx.x & 63;
    int i = (blockIdx.x * 256 + threadIdx.x) >> 6;
    if (i >= N) return;
    float w_self = __expf(leaky(hi[i] + hj[i]) - decodeF(m_n[i]));
    float sn = s_n[i] + w_self;
    float cn = cnt_n[i] + 1.f;
    float vn = (acc_n[(size_t)i * 64 + lane] + w_self * h[(size_t)i * 64 + lane]) / sn / cn;
    float ce = cnt_e[i];
    float ve = 0.f;
    if (ce > 0.f) ve = acc_e[(size_t)i * 64 + lane] / s_e[i] / ce;
    out[(size_t)i * 128 + lane] = leaky(vn);
    out[(size_t)i * 128 + 64 + lane] = leaky(ve);
}

extern "C" void kernel_launch(void* const* d_in, const int* in_sizes, int n_in,
                              void* d_out, int out_size, void* d_ws, size_t ws_size,
                              hipStream_t stream){
    const float* x      = (const float*)d_in[0];
    const float* ea     = (const float*)d_in[1];
    const int*   idx    = (const int*)  d_in[2];
    const float* Wn     = (const float*)d_in[3];
    const float* We     = (const float*)d_in[4];
    const float* a_node = (const float*)d_in[5];
    const float* a_edge = (const float*)d_in[6];
    float* out = (float*)d_out;

    const int N = in_sizes[0] / 128;   // 50000
    const int E = in_sizes[1] / 64;    // 800000

    float* p = (float*)d_ws;
    float* h     = p; p += (size_t)N * 64;
    float* hi    = p; p += N;
    float* hj    = p; p += N;
    float* he    = p; p += N;
    float* ge    = p; p += E;
    unsigned* m_n = (unsigned*)p; p += N;
    unsigned* m_e = (unsigned*)p; p += N;
    float* s_n   = p; p += N;
    float* s_e   = p; p += N;
    float* cnt_n = p; p += N;
    float* cnt_e = p; p += N;
    float* acc_n = p; p += (size_t)N * 64;
    float* acc_e = p; p += (size_t)N * 64;

    k_init<<<1024, 256, 0, stream>>>(s_n, s_e, cnt_n, cnt_e, m_e, acc_n, acc_e, N);
    k_node<<<(N + 3) / 4, 256, 0, stream>>>(x, Wn, a_node, a_edge, h, hi, hj, he, m_n, N);
    k_max<<<(E + 255) / 256, 256, 0, stream>>>(ea, idx, We, a_edge, hi, hj, he, ge, m_n, m_e, cnt_n, cnt_e, E);
    k_acc<<<25000, 256, 0, stream>>>(ea, idx, We, h, hi, hj, he, ge, m_n, m_e, s_n, s_e, acc_n, acc_e, E);
    k_final<<<(N + 3) / 4, 256, 0, stream>>>(h, hi, hj, m_n, s_n, s_e, cnt_n, cnt_e, acc_n, acc_e, out, N);
}